// Round 7
// baseline (569.034 us; speedup 1.0000x reference)
//
#include <hip/hip_runtime.h>
#include <hip/hip_bf16.h>
#include <math.h>

// Problem constants (fixed by setup_inputs)
#define BB 2
#define HH 8
#define LQ 512
#define LK 512
#define DD 32
#define D2 (DD / 2)      // 16 d-pairs
#define C2 2             // d-pairs per LDS chunk
#define NC (D2 / C2)     // 8 chunks
#define WAVES 8          // waves (q-rows) per block

#define LOG2E 1.44269504088896f

static __device__ __forceinline__ float fast_rcp(float x) {
#if __has_builtin(__builtin_amdgcn_rcpf)
  return __builtin_amdgcn_rcpf(x);
#else
  return 1.0f / x;
#endif
}

static __device__ __forceinline__ float fast_exp2(float x) {
#if __has_builtin(__builtin_amdgcn_exp2f)
  return __builtin_amdgcn_exp2f(x);
#else
  return __expf(x * 0.69314718056f);
#endif
}

static __device__ __forceinline__ float rfl(float x) {
  return __int_as_float(__builtin_amdgcn_readfirstlane(__float_as_int(x)));
}

// ---------------------------------------------------------------------------
// Pre-kernel (transposing, d-pair packed):
//   wst4[bh][d2][kk] = {e^-k(2d2), k(2d2)*a(2d2), e^-k(2d2+1), k(2d2+1)*a(2d2+1)}
// Grid: 16 bh * 8 kk-tiles = 128 blocks x 256 threads.
// ---------------------------------------------------------------------------
__global__ __launch_bounds__(256) void gatv2_prek_p(
    const float* __restrict__ k, const float* __restrict__ att,
    float4* __restrict__ wst4) {
  const int bh = blockIdx.x >> 3;          // 0..15
  const int kt = blockIdx.x & 7;           // kk tile of 64
  const int h = bh & (HH - 1);
  const int t = threadIdx.x;

  __shared__ float tile[64][33];           // +1 pad

  const float4* src = (const float4*)(k + ((size_t)bh * LK + kt * 64) * DD);
#pragma unroll
  for (int i = 0; i < 2; ++i) {
    const int idx = t + i * 256;           // 0..511
    const float4 v = src[idx];
    const int kkl = idx >> 3;
    const int d4 = (idx & 7) * 4;
    tile[kkl][d4 + 0] = v.x; tile[kkl][d4 + 1] = v.y;
    tile[kkl][d4 + 2] = v.z; tile[kkl][d4 + 3] = v.w;
  }
  __syncthreads();

  // t -> d2 = t>>4 (0..15), kl0 = (t&15)*4: 4 consecutive kk each
  const int d2 = t >> 4;
  const int kl0 = (t & 15) * 4;
  const float a0 = att[h * DD + 2 * d2 + 0];
  const float a1 = att[h * DD + 2 * d2 + 1];
  float4* dst = wst4 + ((size_t)bh * D2 + d2) * LK + kt * 64 + kl0;
#pragma unroll
  for (int j = 0; j < 4; ++j) {
    const float k0 = tile[kl0 + j][2 * d2 + 0];
    const float k1 = tile[kl0 + j][2 * d2 + 1];
    float4 o;
    o.x = fast_exp2(-k0 * LOG2E); o.y = k0 * a0;
    o.z = fast_exp2(-k1 * LOG2E); o.w = k1 * a1;
    dst[j] = o;
  }
}

// ---------------------------------------------------------------------------
// Main kernel: 8 waves/block, one q-row per wave, all same (b,h) slice.
// wst slice staged chunk-wise into double-buffered LDS (T14 split staging).
// Per element: u = fma(Eq,Ek,1); t = qa+ka; acc = fma(t, rcp(u), acc)
// ---------------------------------------------------------------------------
__global__ __launch_bounds__(512, 8) void gatv2_main_l(
    const float* __restrict__ q, const int* __restrict__ mask,
    const float* __restrict__ bias, const float* __restrict__ att,
    const float4* __restrict__ wst4, float* __restrict__ out) {
  const int lane = threadIdx.x & 63;
  const int wid = threadIdx.x >> 6;        // 0..7
  const int tid = threadIdx.x;             // 0..511
  const int r = blockIdx.x * WAVES + wid;  // ((b*H)+h)*LQ + qi
  const int b = r >> 12;
  const int h = (r >> 9) & (HH - 1);
  const int qi = r & (LQ - 1);
  const int bh = b * HH + h;               // same for all waves in block

  __shared__ float4 lds4[2][C2 * LK];      // 2 x 16 KB

  const float* __restrict__ qrow = q + (size_t)r * DD;
  const float* __restrict__ arow = att + h * DD;
  const float4* __restrict__ kb = wst4 + (size_t)bh * (D2 * LK);

  // Row-uniform per-d constants -> SGPRs
  float sEq[DD], sQa[DD];
#pragma unroll
  for (int d0 = 0; d0 < DD; d0 += 4) {
    const float4 qq = *(const float4*)(qrow + d0);
    const float4 aa = *(const float4*)(arow + d0);
    const float qf[4] = {qq.x, qq.y, qq.z, qq.w};
    const float af[4] = {aa.x, aa.y, aa.z, aa.w};
#pragma unroll
    for (int j = 0; j < 4; ++j) {
      sEq[d0 + j] = rfl(fast_exp2(-qf[j] * LOG2E));
      sQa[d0 + j] = rfl(qf[j] * af[j]);
    }
  }

  float acc[8];
#pragma unroll
  for (int c = 0; c < 8; ++c) acc[c] = 0.0f;

  // --- prologue: stage chunk 0 (each thread: 2 float4) ---
  {
    const float4 s0 = kb[tid];
    const float4 s1 = kb[tid + 512];
    lds4[0][tid] = s0;
    lds4[0][tid + 512] = s1;
  }

#pragma unroll
  for (int cc = 0; cc < NC; ++cc) {
    __syncthreads();                       // chunk cc staged; prev buffer free

    float4 s0, s1;
    if (cc + 1 < NC) {                     // issue next-chunk loads early (T14)
      const float4* src = kb + (size_t)(cc + 1) * (C2 * LK);
      s0 = src[tid];
      s1 = src[tid + 512];
    }

    // compute chunk cc from lds4[cc&1]
    const float4* __restrict__ buf = lds4[cc & 1];
#pragma unroll
    for (int d2l = 0; d2l < C2; ++d2l) {
      const int d = (cc * C2 + d2l) * 2;
      const float eq0 = sEq[d], qa0 = sQa[d];
      const float eq1 = sEq[d + 1], qa1 = sQa[d + 1];
      const float4* __restrict__ pd = buf + d2l * LK + lane;
#pragma unroll
      for (int c = 0; c < 8; ++c) {
        const float4 p = pd[64 * c];       // linear ds_read_b128
        const float u0 = fmaf(eq0, p.x, 1.0f);
        const float t0 = qa0 + p.y;
        acc[c] = fmaf(t0, fast_rcp(u0), acc[c]);
        const float u1 = fmaf(eq1, p.z, 1.0f);
        const float t1 = qa1 + p.w;
        acc[c] = fmaf(t1, fast_rcp(u1), acc[c]);
      }
    }

    if (cc + 1 < NC) {                     // write next chunk after compute
      float4* dst = lds4[(cc + 1) & 1];
      dst[tid] = s0;
      dst[tid + 512] = s1;
    }
  }

  // --- epilogue: bias + mask + wave softmax ---
  const float* __restrict__ brow = bias + (size_t)r * LK;
  const int* __restrict__ mrow = mask + ((size_t)(b * LQ + qi)) * LK;

  float sc[8];
#pragma unroll
  for (int c = 0; c < 8; ++c) {
    const float bval = brow[lane + 64 * c];
    const int mval = mrow[lane + 64 * c];
    sc[c] = mval ? -INFINITY : (acc[c] + bval);
  }

  float m = sc[0];
#pragma unroll
  for (int c = 1; c < 8; ++c) m = fmaxf(m, sc[c]);
#pragma unroll
  for (int off = 32; off > 0; off >>= 1)
    m = fmaxf(m, __shfl_xor(m, off, 64));

  float sum = 0.0f;
#pragma unroll
  for (int c = 0; c < 8; ++c) {
    const float p = fast_exp2((sc[c] - m) * LOG2E);
    sc[c] = p;
    sum += p;
  }
#pragma unroll
  for (int off = 32; off > 0; off >>= 1)
    sum += __shfl_xor(sum, off, 64);

  const bool dead = (m == -INFINITY);
  const float inv = dead ? 0.0f : fast_rcp(sum);

  float* __restrict__ orow = out + (size_t)r * LK;
#pragma unroll
  for (int c = 0; c < 8; ++c) {
    orow[lane + 64 * c] = dead ? 0.0f : sc[c] * inv;
  }
}

// ---------------------------------------------------------------------------
// Fallback (proven R2 kernel) in case ws_size < 2 MB.
// ---------------------------------------------------------------------------
__global__ __launch_bounds__(256) void gatv2_fallback(
    const float* __restrict__ q, const float* __restrict__ k,
    const int* __restrict__ mask, const float* __restrict__ bias,
    const float* __restrict__ att, float* __restrict__ out) {
  const int lane = threadIdx.x & 63;
  const int wid = threadIdx.x >> 6;
  const int r = blockIdx.x * 4 + wid;
  const int b = r >> 12;
  const int h = (r >> 9) & (HH - 1);
  const int qi = r & (LQ - 1);

  const float* __restrict__ qrow = q + (size_t)r * DD;
  const float* __restrict__ kbase = k + ((size_t)(b * HH + h)) * (size_t)(LK * DD);
  const float* __restrict__ arow = att + h * DD;
  const float* __restrict__ brow = bias + (size_t)r * LK;
  const int* __restrict__ mrow = mask + ((size_t)(b * LQ + qi)) * LK;

  float qv[DD], av[DD];
#pragma unroll
  for (int d0 = 0; d0 < DD; d0 += 4) {
    const float4 qq = *(const float4*)(qrow + d0);
    const float4 aa = *(const float4*)(arow + d0);
    qv[d0 + 0] = qq.x; qv[d0 + 1] = qq.y; qv[d0 + 2] = qq.z; qv[d0 + 3] = qq.w;
    av[d0 + 0] = aa.x; av[d0 + 1] = aa.y; av[d0 + 2] = aa.z; av[d0 + 3] = aa.w;
  }

  float sc[8];
#pragma unroll
  for (int c = 0; c < 8; ++c) {
    const int kk = lane + 64 * c;
    const float* __restrict__ kr = kbase + (size_t)kk * DD;
    const float bval = brow[kk];
    const int mval = mrow[kk];
    float acc = 0.0f;
#pragma unroll
    for (int d0 = 0; d0 < DD; d0 += 4) {
      const float4 kv = *(const float4*)(kr + d0);
      const float kvf[4] = {kv.x, kv.y, kv.z, kv.w};
#pragma unroll
      for (int j = 0; j < 4; ++j) {
        const float t = qv[d0 + j] + kvf[j];
        const float e = fast_exp2(t * -LOG2E);
        const float sg = fast_rcp(1.0f + e);
        acc = fmaf(t * sg, av[d0 + j], acc);
      }
    }
    const float s = acc + bval;
    sc[c] = mval ? -INFINITY : s;
  }

  float m = sc[0];
#pragma unroll
  for (int c = 1; c < 8; ++c) m = fmaxf(m, sc[c]);
#pragma unroll
  for (int off = 32; off > 0; off >>= 1)
    m = fmaxf(m, __shfl_xor(m, off, 64));

  float sum = 0.0f;
#pragma unroll
  for (int c = 0; c < 8; ++c) {
    const float p = fast_exp2((sc[c] - m) * LOG2E);
    sc[c] = p;
    sum += p;
  }
#pragma unroll
  for (int off = 32; off > 0; off >>= 1)
    sum += __shfl_xor(sum, off, 64);

  const bool dead = (m == -INFINITY);
  const float inv = dead ? 0.0f : fast_rcp(sum);

  float* __restrict__ orow = out + (size_t)r * LK;
#pragma unroll
  for (int c = 0; c < 8; ++c) {
    orow[lane + 64 * c] = dead ? 0.0f : sc[c] * inv;
  }
}

extern "C" void kernel_launch(void* const* d_in, const int* in_sizes, int n_in,
                              void* d_out, int out_size, void* d_ws, size_t ws_size,
                              hipStream_t stream) {
  const float* q = (const float*)d_in[0];
  const float* k = (const float*)d_in[1];
  // d_in[2] = scale, unused
  const int* mask = (const int*)d_in[3];
  const float* bias = (const float*)d_in[4];
  const float* att = (const float*)d_in[5];
  float* out = (float*)d_out;

  const int rows = BB * HH * LQ;                          // 8192
  const size_t ws_needed = (size_t)BB * HH * D2 * LK * sizeof(float4);  // 2 MB

  if (ws_size >= ws_needed) {
    float4* wst4 = (float4*)d_ws;
    gatv2_prek_p<<<dim3(128), dim3(256), 0, stream>>>(k, att, wst4);
    gatv2_main_l<<<dim3(rows / WAVES), dim3(64 * WAVES), 0, stream>>>(
        q, mask, bias, att, wst4, out);
  } else {
    gatv2_fallback<<<dim3(rows / 4), dim3(256), 0, stream>>>(q, k, mask, bias, att, out);
  }
}

// Round 11
// 101.057 us; speedup vs baseline: 5.6308x; 5.6308x over previous
//
#include <hip/hip_runtime.h>
#include <hip/hip_bf16.h>
#include <math.h>

// Problem constants (fixed by setup_inputs)
#define BB 2
#define HH 8
#define LQ 512
#define LK 512
#define DD 32
#define D2 (DD / 2)      // 16 d-pairs
#define C2 2             // d-pairs per LDS chunk (chunk = 4 d's = 16 KB)
#define NC (D2 / C2)     // 8 chunks
#define WAVES 8          // waves per block
#define RPW 2            // q-rows per wave
#define ROWSPB (WAVES * RPW)  // 16 rows per block

#define LOG2E 1.44269504088896f

static __device__ __forceinline__ float fast_rcp(float x) {
#if __has_builtin(__builtin_amdgcn_rcpf)
  return __builtin_amdgcn_rcpf(x);
#else
  return 1.0f / x;
#endif
}

static __device__ __forceinline__ float fast_exp2(float x) {
#if __has_builtin(__builtin_amdgcn_exp2f)
  return __builtin_amdgcn_exp2f(x);
#else
  return __expf(x * 0.69314718056f);
#endif
}

// ---------------------------------------------------------------------------
// Pre-kernel (transposing, d-pair packed):
//   wst4[bh][d2][kk] = {e^-k(2d2), k(2d2)*a(2d2), e^-k(2d2+1), k(2d2+1)*a(2d2+1)}
// ---------------------------------------------------------------------------
__global__ __launch_bounds__(256) void gatv2_prek_p(
    const float* __restrict__ k, const float* __restrict__ att,
    float4* __restrict__ wst4) {
  const int bh = blockIdx.x >> 3;          // 0..15
  const int kt = blockIdx.x & 7;           // kk tile of 64
  const int h = bh & (HH - 1);
  const int t = threadIdx.x;

  __shared__ float tile[64][33];           // +1 pad

  const float4* src = (const float4*)(k + ((size_t)bh * LK + kt * 64) * DD);
#pragma unroll
  for (int i = 0; i < 2; ++i) {
    const int idx = t + i * 256;           // 0..511
    const float4 v = src[idx];
    const int kkl = idx >> 3;
    const int d4 = (idx & 7) * 4;
    tile[kkl][d4 + 0] = v.x; tile[kkl][d4 + 1] = v.y;
    tile[kkl][d4 + 2] = v.z; tile[kkl][d4 + 3] = v.w;
  }
  __syncthreads();

  const int d2 = t >> 4;                   // 0..15
  const int kl0 = (t & 15) * 4;
  const float a0 = att[h * DD + 2 * d2 + 0];
  const float a1 = att[h * DD + 2 * d2 + 1];
  float4* dst = wst4 + ((size_t)bh * D2 + d2) * LK + kt * 64 + kl0;
#pragma unroll
  for (int j = 0; j < 4; ++j) {
    const float k0 = tile[kl0 + j][2 * d2 + 0];
    const float k1 = tile[kl0 + j][2 * d2 + 1];
    float4 o;
    o.x = fast_exp2(-k0 * LOG2E); o.y = k0 * a0;
    o.z = fast_exp2(-k1 * LOG2E); o.w = k1 * a1;
    dst[j] = o;
  }
}

// ---------------------------------------------------------------------------
// Main kernel: 8 waves/block, 2 q-rows per wave (16 rows/block, same bh).
// k-slice staged chunk-wise into double-buffered LDS; each ds_read_b128 is
// reused for both rows. Per-row constants {Eq, q*a} in a 4 KB LDS table,
// read via wave-uniform broadcast ds_read_b128.
// ---------------------------------------------------------------------------
__global__ __launch_bounds__(512) void gatv2_main_r2(
    const float* __restrict__ q, const int* __restrict__ mask,
    const float* __restrict__ bias, const float* __restrict__ att,
    const float4* __restrict__ wst4, float* __restrict__ out) {
  const int lane = threadIdx.x & 63;
  const int wid = threadIdx.x >> 6;        // 0..7
  const int tid = threadIdx.x;             // 0..511
  const int rowbase = blockIdx.x * ROWSPB; // multiple of 16 -> same bh
  const int bh = rowbase >> 9;
  const int b = rowbase >> 12;
  const int h = bh & (HH - 1);

  __shared__ float4 lds4[2][C2 * LK];      // 2 x 16 KB data
  __shared__ float4 cst4[ROWSPB][D2];      // 4 KB row constants {eq,qa}x2 per d-pair

  const float4* __restrict__ kb = wst4 + (size_t)bh * (D2 * LK);

  // stage chunk 0 (global -> reg)
  float4 s0 = kb[tid];
  float4 s1 = kb[tid + 512];

  // row constants: row rw = wid*RPW + (lane>>5), d = lane&31 (all 64 lanes busy)
  {
    const int rw = wid * RPW + (lane >> 5);
    const int d = lane & 31;
    const float qd = q[(size_t)(rowbase + rw) * DD + d];
    const float ad = att[h * DD + d];
    float2 c;
    c.x = fast_exp2(-qd * LOG2E);          // e^{-q_d}
    c.y = qd * ad;                         // q_d * a_d
    ((float2*)cst4)[rw * DD + d] = c;
  }
  lds4[0][tid] = s0;
  lds4[0][tid + 512] = s1;

  float acc[RPW][8];
#pragma unroll
  for (int j = 0; j < RPW; ++j)
#pragma unroll
    for (int c = 0; c < 8; ++c) acc[j][c] = 0.0f;

  float bv[RPW][8];
  int mv[RPW][8];

#pragma unroll
  for (int cc = 0; cc < NC; ++cc) {
    __syncthreads();                       // chunk cc staged by all threads

    float4 s0n, s1n;
    if (cc + 1 < NC) {                     // issue next-chunk loads early
      const float4* src = kb + (size_t)(cc + 1) * (C2 * LK);
      s0n = src[tid];
      s1n = src[tid + 512];
    } else {                               // last chunk: prefetch bias/mask instead
      const float* __restrict__ brow = bias + (size_t)rowbase * LK;
      const int* __restrict__ mrow = mask + ((size_t)(b * LQ) + (rowbase & (LQ - 1))) * LK;
#pragma unroll
      for (int j = 0; j < RPW; ++j) {
        const int rw = wid * RPW + j;
#pragma unroll
        for (int c = 0; c < 8; ++c) {
          bv[j][c] = brow[(size_t)rw * LK + lane + 64 * c];
          mv[j][c] = mrow[(size_t)rw * LK + lane + 64 * c];
        }
      }
    }

    // wave-uniform constants for this chunk's 4 d's (d = 4cc .. 4cc+3)
    const float4 c0A = cst4[wid * RPW + 0][cc * 2 + 0];
    const float4 c0B = cst4[wid * RPW + 0][cc * 2 + 1];
    const float4 c1A = cst4[wid * RPW + 1][cc * 2 + 0];
    const float4 c1B = cst4[wid * RPW + 1][cc * 2 + 1];

    const float4* __restrict__ buf = lds4[cc & 1];
#pragma unroll
    for (int d2l = 0; d2l < C2; ++d2l) {
      const float4 k0 = d2l ? c0B : c0A;   // row 0 consts for this d-pair
      const float4 k1 = d2l ? c1B : c1A;   // row 1 consts
      const float4* __restrict__ pd = buf + d2l * LK + lane;
#pragma unroll
      for (int c = 0; c < 8; ++c) {
        const float4 p = pd[64 * c];       // {Ek0, ka0, Ek1, ka1} — reused 2 rows
        // row 0
        float u = fmaf(k0.x, p.x, 1.0f);
        float t = k0.y + p.y;
        acc[0][c] = fmaf(t, fast_rcp(u), acc[0][c]);
        u = fmaf(k0.z, p.z, 1.0f);
        t = k0.w + p.w;
        acc[0][c] = fmaf(t, fast_rcp(u), acc[0][c]);
        // row 1
        u = fmaf(k1.x, p.x, 1.0f);
        t = k1.y + p.y;
        acc[1][c] = fmaf(t, fast_rcp(u), acc[1][c]);
        u = fmaf(k1.z, p.z, 1.0f);
        t = k1.w + p.w;
        acc[1][c] = fmaf(t, fast_rcp(u), acc[1][c]);
      }
    }

    if (cc + 1 < NC) {                     // write next chunk after compute
      float4* dst = lds4[(cc + 1) & 1];
      dst[tid] = s0n;
      dst[tid + 512] = s1n;
    }
  }

  // --- epilogue: per-row masked softmax + store ---
#pragma unroll
  for (int j = 0; j < RPW; ++j) {
    const int r = rowbase + wid * RPW + j;

    float sc[8];
#pragma unroll
    for (int c = 0; c < 8; ++c)
      sc[c] = mv[j][c] ? -INFINITY : (acc[j][c] + bv[j][c]);

    float m = sc[0];
#pragma unroll
    for (int c = 1; c < 8; ++c) m = fmaxf(m, sc[c]);
#pragma unroll
    for (int off = 32; off > 0; off >>= 1)
      m = fmaxf(m, __shfl_xor(m, off, 64));

    float sum = 0.0f;
#pragma unroll
    for (int c = 0; c < 8; ++c) {
      const float p = fast_exp2((sc[c] - m) * LOG2E);
      sc[c] = p;
      sum += p;
    }
#pragma unroll
    for (int off = 32; off > 0; off >>= 1)
      sum += __shfl_xor(sum, off, 64);

    const bool dead = (m == -INFINITY);
    const float inv = dead ? 0.0f : fast_rcp(sum);

    float* __restrict__ orow = out + (size_t)r * LK;
#pragma unroll
    for (int c = 0; c < 8; ++c) {
      orow[lane + 64 * c] = dead ? 0.0f : sc[c] * inv;
    }
  }
}

// ---------------------------------------------------------------------------
// Fallback (proven R2 kernel) in case ws_size < 2 MB.
// ---------------------------------------------------------------------------
__global__ __launch_bounds__(256) void gatv2_fallback(
    const float* __restrict__ q, const float* __restrict__ k,
    const int* __restrict__ mask, const float* __restrict__ bias,
    const float* __restrict__ att, float* __restrict__ out) {
  const int lane = threadIdx.x & 63;
  const int wid = threadIdx.x >> 6;
  const int r = blockIdx.x * 4 + wid;
  const int b = r >> 12;
  const int h = (r >> 9) & (HH - 1);
  const int qi = r & (LQ - 1);

  const float* __restrict__ qrow = q + (size_t)r * DD;
  const float* __restrict__ kbase = k + ((size_t)(b * HH + h)) * (size_t)(LK * DD);
  const float* __restrict__ arow = att + h * DD;
  const float* __restrict__ brow = bias + (size_t)r * LK;
  const int* __restrict__ mrow = mask + ((size_t)(b * LQ + qi)) * LK;

  float qv[DD], av[DD];
#pragma unroll
  for (int d0 = 0; d0 < DD; d0 += 4) {
    const float4 qq = *(const float4*)(qrow + d0);
    const float4 aa = *(const float4*)(arow + d0);
    qv[d0 + 0] = qq.x; qv[d0 + 1] = qq.y; qv[d0 + 2] = qq.z; qv[d0 + 3] = qq.w;
    av[d0 + 0] = aa.x; av[d0 + 1] = aa.y; av[d0 + 2] = aa.z; av[d0 + 3] = aa.w;
  }

  float sc[8];
#pragma unroll
  for (int c = 0; c < 8; ++c) {
    const int kk = lane + 64 * c;
    const float* __restrict__ kr = kbase + (size_t)kk * DD;
    const float bval = brow[kk];
    const int mval = mrow[kk];
    float acc = 0.0f;
#pragma unroll
    for (int d0 = 0; d0 < DD; d0 += 4) {
      const float4 kv = *(const float4*)(kr + d0);
      const float kvf[4] = {kv.x, kv.y, kv.z, kv.w};
#pragma unroll
      for (int j = 0; j < 4; ++j) {
        const float t = qv[d0 + j] + kvf[j];
        const float e = fast_exp2(t * -LOG2E);
        const float sg = fast_rcp(1.0f + e);
        acc = fmaf(t * sg, av[d0 + j], acc);
      }
    }
    const float s = acc + bval;
    sc[c] = mval ? -INFINITY : s;
  }

  float m = sc[0];
#pragma unroll
  for (int c = 1; c < 8; ++c) m = fmaxf(m, sc[c]);
#pragma unroll
  for (int off = 32; off > 0; off >>= 1)
    m = fmaxf(m, __shfl_xor(m, off, 64));

  float sum = 0.0f;
#pragma unroll
  for (int c = 0; c < 8; ++c) {
    const float p = fast_exp2((sc[c] - m) * LOG2E);
    sc[c] = p;
    sum += p;
  }
#pragma unroll
  for (int off = 32; off > 0; off >>= 1)
    sum += __shfl_xor(sum, off, 64);

  const bool dead = (m == -INFINITY);
  const float inv = dead ? 0.0f : fast_rcp(sum);

  float* __restrict__ orow = out + (size_t)r * LK;
#pragma unroll
  for (int c = 0; c < 8; ++c) {
    orow[lane + 64 * c] = dead ? 0.0f : sc[c] * inv;
  }
}

extern "C" void kernel_launch(void* const* d_in, const int* in_sizes, int n_in,
                              void* d_out, int out_size, void* d_ws, size_t ws_size,
                              hipStream_t stream) {
  const float* q = (const float*)d_in[0];
  const float* k = (const float*)d_in[1];
  // d_in[2] = scale, unused
  const int* mask = (const int*)d_in[3];
  const float* bias = (const float*)d_in[4];
  const float* att = (const float*)d_in[5];
  float* out = (float*)d_out;

  const int rows = BB * HH * LQ;                          // 8192
  const size_t ws_needed = (size_t)BB * HH * D2 * LK * sizeof(float4);  // 2 MB

  if (ws_size >= ws_needed) {
    float4* wst4 = (float4*)d_ws;
    gatv2_prek_p<<<dim3(128), dim3(256), 0, stream>>>(k, att, wst4);
    gatv2_main_r2<<<dim3(rows / ROWSPB), dim3(64 * WAVES), 0, stream>>>(
        q, mask, bias, att, wst4, out);
  } else {
    gatv2_fallback<<<dim3(rows / 4), dim3(256), 0, stream>>>(q, k, mask, bias, att, out);
  }
}